// Round 5
// baseline (577.178 us; speedup 1.0000x reference)
//
#include <hip/hip_runtime.h>
#include <stdint.h>

typedef __bf16 bf16x8_t __attribute__((ext_vector_type(8)));
typedef float f32x4_t __attribute__((ext_vector_type(4)));
typedef unsigned short ushort8_t __attribute__((ext_vector_type(8)));

#define DEV __device__ __forceinline__

DEV unsigned short f2bf(float f) {
  union { float f; uint32_t u; } v; v.f = f;
  uint32_t r = v.u + 0x7FFFu + ((v.u >> 16) & 1u);
  return (unsigned short)(r >> 16);
}

DEV void gl_lds16(const void* g, void* l) {
  __builtin_amdgcn_global_load_lds(
      (const __attribute__((address_space(1))) void*)g,
      (__attribute__((address_space(3))) void*)l, 16, 0, 0);
}

// exact-gelu via branch-free A&S 7.1.26 erf (max err 1.5e-7)
DEV float gelu_f(float x) {
  const float y = x * 0.7071067811865475f;
  const float ay = fabsf(y);
  const float t = __builtin_amdgcn_rcpf(1.0f + 0.3275911f * ay);
  float p = fmaf(t, 1.061405429f, -1.453152027f);
  p = fmaf(t, p, 1.421413741f);
  p = fmaf(t, p, -0.284496736f);
  p = fmaf(t, p, 0.254829592f);
  p *= t;
  const float e = __expf(-ay * ay);
  float erfv = 1.0f - p * e;
  erfv = copysignf(erfv, y);
  return 0.5f * x * (1.0f + erfv);
}

// ---------------- fused weight fp32 -> bf16 ----------------
__global__ __launch_bounds__(256) void cvt_all(const float* __restrict__ w0, unsigned short* __restrict__ o0,
                                               const float* __restrict__ w1, unsigned short* __restrict__ o1,
                                               const float* __restrict__ w2, unsigned short* __restrict__ o2,
                                               const float* __restrict__ w3, unsigned short* __restrict__ o3) {
  int i = blockIdx.x * 256 + threadIdx.x;
  const float* in; unsigned short* outp;
  if (i < 786432) { in = w0; outp = o0; }
  else if (i < 1048576) { in = w1; outp = o1; i -= 786432; }
  else if (i < 2097152) { in = w2; outp = o2; i -= 1048576; }
  else { in = w3; outp = o3; i -= 2097152; }
  float4 v = ((const float4*)in)[i];
  ushort4 o;
  o.x = f2bf(v.x); o.y = f2bf(v.y); o.z = f2bf(v.z); o.w = f2bf(v.w);
  ((ushort4*)outp)[i] = o;
}

// ---------------- layernorm fp32 -> bf16 (1024 cols, wave per row) ----------------
__global__ __launch_bounds__(256) void ln_kernel(const float* __restrict__ x,
                                                 const float* __restrict__ g,
                                                 const float* __restrict__ b,
                                                 unsigned short* __restrict__ outp) {
  const int row = blockIdx.x * 4 + (threadIdx.x >> 6);
  const int lane = threadIdx.x & 63;
  const float4* xr = (const float4*)(x + (size_t)row * 1024);
  float4 v[4];
  float s = 0.f, s2 = 0.f;
#pragma unroll
  for (int j = 0; j < 4; ++j) {
    v[j] = xr[j * 64 + lane];
    s += v[j].x + v[j].y + v[j].z + v[j].w;
    s2 += v[j].x * v[j].x + v[j].y * v[j].y + v[j].z * v[j].z + v[j].w * v[j].w;
  }
#pragma unroll
  for (int off = 1; off < 64; off <<= 1) {
    s += __shfl_xor(s, off, 64);
    s2 += __shfl_xor(s2, off, 64);
  }
  const float mu = s * (1.0f / 1024.0f);
  const float var = s2 * (1.0f / 1024.0f) - mu * mu;
  const float rstd = rsqrtf(var + 1e-5f);
  ushort4* orow = (ushort4*)(outp + (size_t)row * 1024);
  const float4* gp = (const float4*)g;
  const float4* bp = (const float4*)b;
#pragma unroll
  for (int j = 0; j < 4; ++j) {
    float4 gv = gp[j * 64 + lane], bv = bp[j * 64 + lane];
    ushort4 o;
    o.x = f2bf((v[j].x - mu) * rstd * gv.x + bv.x);
    o.y = f2bf((v[j].y - mu) * rstd * gv.y + bv.y);
    o.z = f2bf((v[j].z - mu) * rstd * gv.z + bv.z);
    o.w = f2bf((v[j].w - mu) * rstd * gv.w + bv.w);
    orow[j * 64 + lane] = o;
  }
}

// ---------------- GEMM: C[M,N] = A[M,K] * B[N,K]^T, bf16 in, fp32 acc ----------------
// BK=32, double-buffered LDS, one barrier per K-iter (loads for k+1 in flight
// during compute of k). Wave tile 64x(BN/2): BN=256 -> 12 ds_read per 32 MFMA.
// Swizzle (0 conflicts, verified R2): phys chunk = kc ^ ((row>>1)&3).
// Column-major block order: 64 consecutive blocks = one col-stripe -> per-XCD
// L2 holds one B-tile, streams A.
// MODE 0: bf16 C; V-third (col>=2048) transposed to Vt[b,h,d,t]   (QKV)
// MODE 1: fp32 C = acc + res                                      (proj + residual)
// MODE 2: bf16 C = gelu(acc + bias)                               (FF1)
// MODE 3: fp32 C = acc + bias + res                               (FF2 + residual)
template <int MODE, int BN>
__global__ __launch_bounds__(256) void gemm_bt(const unsigned short* __restrict__ A,
                                               const unsigned short* __restrict__ B,
                                               float* __restrict__ Cf,
                                               unsigned short* __restrict__ Cb,
                                               const float* __restrict__ bias,
                                               const float* __restrict__ res,
                                               unsigned short* __restrict__ Vt,
                                               int M, int N, int K) {
  constexpr int NI = BN / 32;          // b-frags / acc cols per wave
  constexpr int NB = BN / 64;          // B staging slabs
  __shared__ unsigned short sA[2][128 * 32];
  __shared__ unsigned short sB[2][BN * 32];
  const int tid = threadIdx.x;
  const int w = tid >> 6, lane = tid & 63;
  const int kg = lane >> 4, l16 = lane & 15;
  const int wm = (w & 1) * 64, wn = (w >> 1) * (BN / 2);

  // column-major block ordering (gridDim.y = 64 row-tiles)
  const int cid = blockIdx.y * gridDim.x + blockIdx.x;
  const int colBase = (cid >> 6) * BN;
  const int rowBase = (cid & 63) * 128;

  // staging map: thread covers (row sr + 64i, phys chunk tid&3)
  const int sr = tid >> 2;
  const int gc = ((tid & 3) ^ ((sr >> 1) & 3)) * 8;   // swizzled global k-chunk
  const unsigned short* gA = A + (size_t)(rowBase + sr) * K + gc;
  const unsigned short* gB = B + (size_t)(colBase + sr) * K + gc;

  f32x4_t acc[4][NI];
#pragma unroll
  for (int mi = 0; mi < 4; ++mi)
#pragma unroll
    for (int ni = 0; ni < NI; ++ni) acc[mi][ni] = (f32x4_t)0.0f;

  // fragment read offsets within one buffer (shorts)
  int offA[4], offB[NI];
  const int pc = (kg ^ ((l16 >> 1) & 3)) * 8;
#pragma unroll
  for (int i = 0; i < 4; ++i) offA[i] = (wm + i * 16 + l16) * 32 + pc;
#pragma unroll
  for (int i = 0; i < NI; ++i) offB[i] = (wn + i * 16 + l16) * 32 + pc;

  // prologue: tile 0 -> buf 0
#pragma unroll
  for (int i = 0; i < 2; ++i) gl_lds16(gA + (size_t)(64 * i) * K, &sA[0][2048 * i + tid * 8]);
#pragma unroll
  for (int i = 0; i < NB; ++i) gl_lds16(gB + (size_t)(64 * i) * K, &sB[0][2048 * i + tid * 8]);
  gA += 32; gB += 32;

  const int nk = K >> 5;
  for (int kt = 0; kt < nk; ++kt) {
    __syncthreads();  // drains loads for tile kt (in flight during compute kt-1)
    if (kt + 1 < nk) {
      const int nb = (kt + 1) & 1;
#pragma unroll
      for (int i = 0; i < 2; ++i) gl_lds16(gA + (size_t)(64 * i) * K, &sA[nb][2048 * i + tid * 8]);
#pragma unroll
      for (int i = 0; i < NB; ++i) gl_lds16(gB + (size_t)(64 * i) * K, &sB[nb][2048 * i + tid * 8]);
      gA += 32; gB += 32;
    }
    const int cb = kt & 1;
    bf16x8_t a[4], b[NI];
#pragma unroll
    for (int i = 0; i < 4; ++i) a[i] = *(const bf16x8_t*)(&sA[cb][0] + offA[i]);
#pragma unroll
    for (int i = 0; i < NI; ++i) b[i] = *(const bf16x8_t*)(&sB[cb][0] + offB[i]);
#pragma unroll
    for (int mi = 0; mi < 4; ++mi)
#pragma unroll
      for (int ni = 0; ni < NI; ++ni)
        acc[mi][ni] = __builtin_amdgcn_mfma_f32_16x16x32_bf16(a[mi], b[ni], acc[mi][ni], 0, 0, 0);
  }

#pragma unroll
  for (int mi = 0; mi < 4; ++mi) {
#pragma unroll
    for (int ni = 0; ni < NI; ++ni) {
      const int col = colBase + wn + ni * 16 + l16;
      if (MODE == 0 && colBase >= 2048) {
        // V third -> Vt[b,h,d,t]; r-quad is t-contiguous -> ushort4 store
        const int c2 = col - 2048;
        const int hh = c2 >> 6, dd = c2 & 63;
        const int rw = rowBase + wm + mi * 16 + kg * 4;
        ushort4 pk;
        pk.x = f2bf(acc[mi][ni][0]);
        pk.y = f2bf(acc[mi][ni][1]);
        pk.z = f2bf(acc[mi][ni][2]);
        pk.w = f2bf(acc[mi][ni][3]);
        *(ushort4*)(Vt + (((size_t)(rw >> 9) * 16 + hh) * 64 + dd) * 512 + (rw & 511)) = pk;
        continue;
      }
      float bv = 0.f;
      if (MODE == 2 || MODE == 3) bv = bias[col];
#pragma unroll
      for (int r = 0; r < 4; ++r) {
        const int row = rowBase + wm + mi * 16 + kg * 4 + r;
        const size_t idx = (size_t)row * N + col;
        float v = acc[mi][ni][r];
        if (MODE == 0) {
          Cb[idx] = f2bf(v);
        } else if (MODE == 1) {
          Cf[idx] = v + res[idx];
        } else if (MODE == 2) {
          Cb[idx] = f2bf(gelu_f(v + bv));
        } else {
          Cf[idx] = v + bv + res[idx];
        }
      }
    }
  }
}

// ---------------- causal flash attention ----------------
// qkv: [8192, 3072] bf16 (q | k cols; V comes from Vt[b,h,d,t]); out: [8192, 1024] bf16
// sQ/sK/sVt XOR-swizzled: physical chunk for (row r, chunk c in 0..7) = c ^ (r&7)
__global__ __launch_bounds__(256) void attn_kernel(const unsigned short* __restrict__ qkv,
                                                   const unsigned short* __restrict__ Vt,
                                                   unsigned short* __restrict__ outp) {
  constexpr int D3 = 3072;
  __shared__ unsigned short sQ[128 * 64];
  __shared__ unsigned short sK[64 * 64];
  __shared__ unsigned short sVt[64 * 64];   // [d][k-slice]
  __shared__ unsigned short sP[128 * 72];   // [q][k], stride 72
  const int tid = threadIdx.x;
  const int w = tid >> 6, lane = tid & 63;
  const int kg = lane >> 4, l16 = lane & 15;
  const int qi = blockIdx.x, h = blockIdx.y, bb = blockIdx.z;
  const int t0 = qi * 128;
  const size_t base = (size_t)bb * 512 * D3 + h * 64;

  const int sr = tid >> 3;                           // staging row within 32-row slab
  const int sc = ((tid & 7) ^ (sr & 7)) * 8;         // swizzled k-chunk (shorts)

  // stage Q (rows t0..t0+127)
  {
    const unsigned short* g = qkv + base + (size_t)(t0 + sr) * D3 + sc;
    unsigned short* l = sQ + tid * 8;
#pragma unroll
    for (int i = 0; i < 4; ++i) gl_lds16(g + (size_t)32 * i * D3, l + 2048 * i);
  }

  const unsigned short* gVbase = Vt + ((size_t)(bb * 16 + h) * 64 + sr) * 512 + sc;

  const int wm = w * 32;  // wave's 32 q-rows within tile
  f32x4_t o[2][4];
  float m_i[2][4], l_i[2][4];
#pragma unroll
  for (int mi = 0; mi < 2; ++mi)
#pragma unroll
    for (int r = 0; r < 4; ++r) { m_i[mi][r] = -1e30f; l_i[mi][r] = 0.f; }
#pragma unroll
  for (int mi = 0; mi < 2; ++mi)
#pragma unroll
    for (int di = 0; di < 4; ++di) o[mi][di] = (f32x4_t)0.0f;

  const int nkt = (qi + 1) * 2;
  for (int kt = 0; kt < nkt; ++kt) {
    const int k0 = kt * 64;
    __syncthreads();
    // stage K tile [64][64] swizzled
    {
      const unsigned short* g = qkv + base + 1024 + (size_t)(k0 + sr) * D3 + sc;
      unsigned short* l = sK + tid * 8;
      gl_lds16(g, l);
      gl_lds16(g + (size_t)32 * D3, l + 2048);
    }
    // stage Vt tile [64 d][64 k] swizzled (clean rows, no scalar transpose)
    {
      const unsigned short* g = gVbase + k0;
      unsigned short* l = sVt + tid * 8;
      gl_lds16(g, l);
      gl_lds16(g + (size_t)32 * 512, l + 2048);
    }
    __syncthreads();

    const bool active = (k0 <= t0 + wm + 31);
    if (active) {
      // S = Q K^T
      f32x4_t s[2][4];
#pragma unroll
      for (int mi = 0; mi < 2; ++mi)
#pragma unroll
        for (int ni = 0; ni < 4; ++ni) s[mi][ni] = (f32x4_t)0.0f;
#pragma unroll
      for (int kd = 0; kd < 2; ++kd) {
        bf16x8_t aq[2], bk[4];
#pragma unroll
        for (int mi = 0; mi < 2; ++mi) {
          const int rr = wm + mi * 16 + l16;
          aq[mi] = *(const bf16x8_t*)(sQ + rr * 64 + (((kd * 4 + kg) ^ (l16 & 7)) * 8));
        }
#pragma unroll
        for (int ni = 0; ni < 4; ++ni) {
          const int rr = ni * 16 + l16;
          bk[ni] = *(const bf16x8_t*)(sK + rr * 64 + (((kd * 4 + kg) ^ (l16 & 7)) * 8));
        }
#pragma unroll
        for (int mi = 0; mi < 2; ++mi)
#pragma unroll
          for (int ni = 0; ni < 4; ++ni)
            s[mi][ni] = __builtin_amdgcn_mfma_f32_16x16x32_bf16(aq[mi], bk[ni], s[mi][ni], 0, 0, 0);
      }
      // online softmax per row
#pragma unroll
      for (int mi = 0; mi < 2; ++mi) {
#pragma unroll
        for (int r = 0; r < 4; ++r) {
          const int q = t0 + wm + mi * 16 + kg * 4 + r;
          float mx = -1e30f;
#pragma unroll
          for (int ni = 0; ni < 4; ++ni) {
            const int kk = k0 + ni * 16 + l16;
            float v = s[mi][ni][r] * 0.125f;
            v = (kk <= q) ? v : -10000.0f;
            s[mi][ni][r] = v;
            mx = fmaxf(mx, v);
          }
#pragma unroll
          for (int off = 1; off < 16; off <<= 1) mx = fmaxf(mx, __shfl_xor(mx, off, 64));
          const float mo = m_i[mi][r];
          const float mn = fmaxf(mo, mx);
          const float alpha = __expf(mo - mn);
          float ps = 0.f;
#pragma unroll
          for (int ni = 0; ni < 4; ++ni) {
            float p = __expf(s[mi][ni][r] - mn);
            s[mi][ni][r] = p;
            ps += p;
          }
#pragma unroll
          for (int off = 1; off < 16; off <<= 1) ps += __shfl_xor(ps, off, 64);
          l_i[mi][r] = l_i[mi][r] * alpha + ps;
          m_i[mi][r] = mn;
#pragma unroll
          for (int di = 0; di < 4; ++di) o[mi][di][r] *= alpha;
          const int prow = wm + mi * 16 + kg * 4 + r;
#pragma unroll
          for (int ni = 0; ni < 4; ++ni)
            sP[prow * 72 + ni * 16 + l16] = f2bf(s[mi][ni][r]);
        }
      }
      // O += P V   (B-operand = sVt[d][k], vector reads)
#pragma unroll
      for (int kd = 0; kd < 2; ++kd) {
        bf16x8_t ap[2], bv[4];
#pragma unroll
        for (int mi = 0; mi < 2; ++mi)
          ap[mi] = *(const bf16x8_t*)(sP + (wm + mi * 16 + l16) * 72 + kd * 32 + kg * 8);
#pragma unroll
        for (int di = 0; di < 4; ++di) {
          const int dd = di * 16 + l16;
          bv[di] = *(const bf16x8_t*)(sVt + dd * 64 + (((kd * 4 + kg) ^ (l16 & 7)) * 8));
        }
#pragma unroll
        for (int mi = 0; mi < 2; ++mi)
#pragma unroll
          for (int di = 0; di < 4; ++di)
            o[mi][di] = __builtin_amdgcn_mfma_f32_16x16x32_bf16(ap[mi], bv[di], o[mi][di], 0, 0, 0);
      }
    }
  }

  // epilogue: normalize + store bf16
#pragma unroll
  for (int mi = 0; mi < 2; ++mi) {
#pragma unroll
    for (int r = 0; r < 4; ++r) {
      const float inv = 1.0f / l_i[mi][r];
      const int row = t0 + wm + mi * 16 + kg * 4 + r;
      const size_t ob = ((size_t)bb * 512 + row) * 1024 + h * 64;
#pragma unroll
      for (int di = 0; di < 4; ++di)
        outp[ob + di * 16 + l16] = f2bf(o[mi][di][r] * inv);
    }
  }
}

// ---------------- launch ----------------
extern "C" void kernel_launch(void* const* d_in, const int* in_sizes, int n_in,
                              void* d_out, int out_size, void* d_ws, size_t ws_size,
                              hipStream_t stream) {
  const float* x      = (const float*)d_in[0];
  const float* w_qkv  = (const float*)d_in[1];
  const float* w_proj = (const float*)d_in[2];
  const float* w_ff1  = (const float*)d_in[3];
  const float* b_ff1  = (const float*)d_in[4];
  const float* w_ff2  = (const float*)d_in[5];
  const float* b_ff2  = (const float*)d_in[6];
  const float* ln1_g  = (const float*)d_in[7];
  const float* ln1_b  = (const float*)d_in[8];
  const float* ln2_g  = (const float*)d_in[9];
  const float* ln2_b  = (const float*)d_in[10];
  float* out = (float*)d_out;
  char* ws = (char*)d_ws;

  // workspace layout (bytes)
  unsigned short* wqkv_b  = (unsigned short*)(ws + 0);          //  6291456
  unsigned short* wproj_b = (unsigned short*)(ws + 6291456);    //  2097152
  unsigned short* wff1_b  = (unsigned short*)(ws + 8388608);    //  8388608
  unsigned short* wff2_b  = (unsigned short*)(ws + 16777216);   //  8388608
  unsigned short* a_b     = (unsigned short*)(ws + 25165824);   // 16777216 (ln1 out, reused for ln2 out)
  float*          x2_f    = (float*)(ws + 41943040);            // 33554432 (dead until proj)
  unsigned short* vt_b    = (unsigned short*)(ws + 41943040);   // 16777216 alias: live QKV->attn only
  unsigned short* qkv_b   = (unsigned short*)(ws + 75497472);   // 50331648
  unsigned short* attn_b  = (unsigned short*)(ws + 125829120);  // 16777216
  unsigned short* h_b     = qkv_b;                              // 67108864 spans qkv+attn (both dead by FF1)

  // weights fp32 -> bf16 (one fused launch)
  cvt_all<<<12288, 256, 0, stream>>>(w_qkv, wqkv_b, w_proj, wproj_b, w_ff1, wff1_b, w_ff2, wff2_b);

  // LN1
  ln_kernel<<<2048, 256, 0, stream>>>(x, ln1_g, ln1_b, a_b);
  // QKV (V third written transposed to vt_b)
  gemm_bt<0, 256><<<dim3(12, 64), 256, 0, stream>>>(a_b, wqkv_b, nullptr, qkv_b, nullptr, nullptr, vt_b, 8192, 3072, 1024);
  // attention
  attn_kernel<<<dim3(4, 16, 16), 256, 0, stream>>>(qkv_b, vt_b, attn_b);
  // proj + residual
  gemm_bt<1, 128><<<dim3(8, 64), 256, 0, stream>>>(attn_b, wproj_b, x2_f, nullptr, nullptr, x, nullptr, 8192, 1024, 1024);
  // LN2
  ln_kernel<<<2048, 256, 0, stream>>>(x2_f, ln2_g, ln2_b, a_b);
  // FF1 + bias + gelu
  gemm_bt<2, 256><<<dim3(16, 64), 256, 0, stream>>>(a_b, wff1_b, nullptr, h_b, b_ff1, nullptr, nullptr, 8192, 4096, 1024);
  // FF2 + bias + residual
  gemm_bt<3, 128><<<dim3(8, 64), 256, 0, stream>>>(h_b, wff2_b, out, nullptr, b_ff2, x2_f, nullptr, 8192, 1024, 4096);
}

// Round 8
// 478.015 us; speedup vs baseline: 1.2074x; 1.2074x over previous
//
#include <hip/hip_runtime.h>
#include <stdint.h>

typedef __bf16 bf16x8_t __attribute__((ext_vector_type(8)));
typedef float f32x4_t __attribute__((ext_vector_type(4)));
typedef unsigned short ushort8_t __attribute__((ext_vector_type(8)));

#define DEV __device__ __forceinline__

DEV unsigned short f2bf(float f) {
  union { float f; uint32_t u; } v; v.f = f;
  uint32_t r = v.u + 0x7FFFu + ((v.u >> 16) & 1u);
  return (unsigned short)(r >> 16);
}

// NOTE: the intrinsic's offset arg applies to BOTH global and LDS address
// (R6 failure: absmax 984). Keep it 0 always.
DEV void gl_lds16(const void* g, void* l) {
  __builtin_amdgcn_global_load_lds(
      (const __attribute__((address_space(1))) void*)g,
      (__attribute__((address_space(3))) void*)l, 16, 0, 0);
}

// exact-gelu via branch-free A&S 7.1.26 erf (max err 1.5e-7)
DEV float gelu_f(float x) {
  const float y = x * 0.7071067811865475f;
  const float ay = fabsf(y);
  const float t = __builtin_amdgcn_rcpf(1.0f + 0.3275911f * ay);
  float p = fmaf(t, 1.061405429f, -1.453152027f);
  p = fmaf(t, p, 1.421413741f);
  p = fmaf(t, p, -0.284496736f);
  p = fmaf(t, p, 0.254829592f);
  p *= t;
  const float e = __expf(-ay * ay);
  float erfv = 1.0f - p * e;
  erfv = copysignf(erfv, y);
  return 0.5f * x * (1.0f + erfv);
}

// ---------------- fused weight fp32 -> bf16 ----------------
__global__ __launch_bounds__(256) void cvt_all(const float* __restrict__ w0, unsigned short* __restrict__ o0,
                                               const float* __restrict__ w1, unsigned short* __restrict__ o1,
                                               const float* __restrict__ w2, unsigned short* __restrict__ o2,
                                               const float* __restrict__ w3, unsigned short* __restrict__ o3) {
  int i = blockIdx.x * 256 + threadIdx.x;
  const float* in; unsigned short* outp;
  if (i < 786432) { in = w0; outp = o0; }
  else if (i < 1048576) { in = w1; outp = o1; i -= 786432; }
  else if (i < 2097152) { in = w2; outp = o2; i -= 1048576; }
  else { in = w3; outp = o3; i -= 2097152; }
  float4 v = ((const float4*)in)[i];
  ushort4 o;
  o.x = f2bf(v.x); o.y = f2bf(v.y); o.z = f2bf(v.z); o.w = f2bf(v.w);
  ((ushort4*)outp)[i] = o;
}

// ---------------- layernorm fp32 -> bf16 (1024 cols, wave per row) ----------------
__global__ __launch_bounds__(256) void ln_kernel(const float* __restrict__ x,
                                                 const float* __restrict__ g,
                                                 const float* __restrict__ b,
                                                 unsigned short* __restrict__ outp) {
  const int row = blockIdx.x * 4 + (threadIdx.x >> 6);
  const int lane = threadIdx.x & 63;
  const float4* xr = (const float4*)(x + (size_t)row * 1024);
  float4 v[4];
  float s = 0.f, s2 = 0.f;
#pragma unroll
  for (int j = 0; j < 4; ++j) {
    v[j] = xr[j * 64 + lane];
    s += v[j].x + v[j].y + v[j].z + v[j].w;
    s2 += v[j].x * v[j].x + v[j].y * v[j].y + v[j].z * v[j].z + v[j].w * v[j].w;
  }
#pragma unroll
  for (int off = 1; off < 64; off <<= 1) {
    s += __shfl_xor(s, off, 64);
    s2 += __shfl_xor(s2, off, 64);
  }
  const float mu = s * (1.0f / 1024.0f);
  const float var = s2 * (1.0f / 1024.0f) - mu * mu;
  const float rstd = rsqrtf(var + 1e-5f);
  ushort4* orow = (ushort4*)(outp + (size_t)row * 1024);
  const float4* gp = (const float4*)g;
  const float4* bp = (const float4*)b;
#pragma unroll
  for (int j = 0; j < 4; ++j) {
    float4 gv = gp[j * 64 + lane], bv = bp[j * 64 + lane];
    ushort4 o;
    o.x = f2bf((v[j].x - mu) * rstd * gv.x + bv.x);
    o.y = f2bf((v[j].y - mu) * rstd * gv.y + bv.y);
    o.z = f2bf((v[j].z - mu) * rstd * gv.z + bv.z);
    o.w = f2bf((v[j].w - mu) * rstd * gv.w + bv.w);
    orow[j * 64 + lane] = o;
  }
}

// ---------------- GEMM: C[M,N] = A[M,K] * B[N,K]^T, bf16 in, fp32 acc ----------------
// EXACT R4-proven K-loop: BK=32, double-buffered LDS, one barrier per iter
// (loads for tile k+1 in flight during compute of tile k). Runtime K.
// Swizzle (0 conflicts, verified R2): phys chunk = kc ^ ((row>>1)&3).
// Column-major block order (verified R5: FETCH 107->62 MB per FF1 dispatch).
// MODE 0: bf16 C; V-third (col>=2048) transposed to Vt[b,h,d,t]   (QKV)
// MODE 1: fp32 C = acc + res                                      (proj + residual)
// MODE 2: bf16 C = gelu(acc + bias)                               (FF1)
// MODE 3: fp32 C = acc + bias + res                               (FF2 + residual)
template <int MODE>
__global__ __launch_bounds__(256) void gemm_bt(const unsigned short* __restrict__ A,
                                               const unsigned short* __restrict__ B,
                                               float* __restrict__ Cf,
                                               unsigned short* __restrict__ Cb,
                                               const float* __restrict__ bias,
                                               const float* __restrict__ res,
                                               unsigned short* __restrict__ Vt,
                                               int M, int N, int K) {
  __shared__ unsigned short sA[2][128 * 32];
  __shared__ unsigned short sB[2][128 * 32];
  const int tid = threadIdx.x;
  const int w = tid >> 6, lane = tid & 63;
  const int kg = lane >> 4, l16 = lane & 15;
  const int wm = (w & 1) * 64, wn = (w >> 1) * 64;

  // column-major block ordering: 64 consecutive blocks share one 128-col B-stripe
  const int cid = blockIdx.y * gridDim.x + blockIdx.x;
  const int colBase = (cid >> 6) * 128;
  const int rowBase = (cid & 63) * 128;

  // staging map: thread covers (row sr + 64i, phys chunk tid&3)
  const int sr = tid >> 2;
  const int gc = ((tid & 3) ^ ((sr >> 1) & 3)) * 8;   // swizzled global k-chunk
  const unsigned short* gA = A + (size_t)(rowBase + sr) * K + gc;
  const unsigned short* gB = B + (size_t)(colBase + sr) * K + gc;

  f32x4_t acc[4][4];
#pragma unroll
  for (int mi = 0; mi < 4; ++mi)
#pragma unroll
    for (int ni = 0; ni < 4; ++ni) acc[mi][ni] = (f32x4_t)0.0f;

  // fragment read offsets within one buffer (shorts)
  int offA[4], offB[4];
  const int pc = (kg ^ ((l16 >> 1) & 3)) * 8;
#pragma unroll
  for (int i = 0; i < 4; ++i) {
    offA[i] = (wm + i * 16 + l16) * 32 + pc;
    offB[i] = (wn + i * 16 + l16) * 32 + pc;
  }

  // prologue: tile 0 -> buf 0
  gl_lds16(gA, &sA[0][tid * 8]);
  gl_lds16(gA + (size_t)64 * K, &sA[0][2048 + tid * 8]);
  gl_lds16(gB, &sB[0][tid * 8]);
  gl_lds16(gB + (size_t)64 * K, &sB[0][2048 + tid * 8]);
  gA += 32; gB += 32;

  const int nk = K >> 5;
  for (int kt = 0; kt < nk; ++kt) {
    __syncthreads();  // drains loads for tile kt (in flight during compute kt-1)
    if (kt + 1 < nk) {
      const int nb = (kt + 1) & 1;
      gl_lds16(gA, &sA[nb][tid * 8]);
      gl_lds16(gA + (size_t)64 * K, &sA[nb][2048 + tid * 8]);
      gl_lds16(gB, &sB[nb][tid * 8]);
      gl_lds16(gB + (size_t)64 * K, &sB[nb][2048 + tid * 8]);
      gA += 32; gB += 32;
    }
    const int bo = (kt & 1) * (128 * 32);
    bf16x8_t a[4], b[4];
#pragma unroll
    for (int i = 0; i < 4; ++i) a[i] = *(const bf16x8_t*)(&sA[0][0] + bo + offA[i]);
#pragma unroll
    for (int i = 0; i < 4; ++i) b[i] = *(const bf16x8_t*)(&sB[0][0] + bo + offB[i]);
#pragma unroll
    for (int mi = 0; mi < 4; ++mi)
#pragma unroll
      for (int ni = 0; ni < 4; ++ni)
        acc[mi][ni] = __builtin_amdgcn_mfma_f32_16x16x32_bf16(a[mi], b[ni], acc[mi][ni], 0, 0, 0);
  }

#pragma unroll
  for (int mi = 0; mi < 4; ++mi) {
#pragma unroll
    for (int ni = 0; ni < 4; ++ni) {
      const int col = colBase + wn + ni * 16 + l16;
      if (MODE == 0 && colBase >= 2048) {
        // V third -> Vt[b,h,d,t]; r-quad is t-contiguous -> ushort4 store
        const int c2 = col - 2048;
        const int hh = c2 >> 6, dd = c2 & 63;
        const int rw = rowBase + wm + mi * 16 + kg * 4;
        ushort4 pk;
        pk.x = f2bf(acc[mi][ni][0]);
        pk.y = f2bf(acc[mi][ni][1]);
        pk.z = f2bf(acc[mi][ni][2]);
        pk.w = f2bf(acc[mi][ni][3]);
        *(ushort4*)(Vt + (((size_t)(rw >> 9) * 16 + hh) * 64 + dd) * 512 + (rw & 511)) = pk;
        continue;
      }
      float bv = 0.f;
      if (MODE == 2 || MODE == 3) bv = bias[col];
#pragma unroll
      for (int r = 0; r < 4; ++r) {
        const int row = rowBase + wm + mi * 16 + kg * 4 + r;
        const size_t idx = (size_t)row * N + col;
        float v = acc[mi][ni][r];
        if (MODE == 0) {
          Cb[idx] = f2bf(v);
        } else if (MODE == 1) {
          Cf[idx] = v + res[idx];
        } else if (MODE == 2) {
          Cb[idx] = f2bf(gelu_f(v + bv));
        } else {
          Cf[idx] = v + bv + res[idx];
        }
      }
    }
  }
}

// ---------------- causal flash attention ----------------
// qkv: [8192, 3072] bf16 (q | k cols; V comes from Vt[b,h,d,t]); out: [8192, 1024] bf16
// sQ/sK/sVt XOR-swizzled: physical chunk for (row r, chunk c in 0..7) = c ^ (r&7)
__global__ __launch_bounds__(256) void attn_kernel(const unsigned short* __restrict__ qkv,
                                                   const unsigned short* __restrict__ Vt,
                                                   unsigned short* __restrict__ outp) {
  constexpr int D3 = 3072;
  __shared__ unsigned short sQ[128 * 64];
  __shared__ unsigned short sK[64 * 64];
  __shared__ unsigned short sVt[64 * 64];   // [d][k-slice]
  __shared__ unsigned short sP[128 * 72];   // [q][k], stride 72
  const int tid = threadIdx.x;
  const int w = tid >> 6, lane = tid & 63;
  const int kg = lane >> 4, l16 = lane & 15;
  const int qi = blockIdx.x, h = blockIdx.y, bb = blockIdx.z;
  const int t0 = qi * 128;
  const size_t base = (size_t)bb * 512 * D3 + h * 64;

  const int sr = tid >> 3;                           // staging row within 32-row slab
  const int sc = ((tid & 7) ^ (sr & 7)) * 8;         // swizzled k-chunk (shorts)

  // stage Q (rows t0..t0+127)
  {
    const unsigned short* g = qkv + base + (size_t)(t0 + sr) * D3 + sc;
    unsigned short* l = sQ + tid * 8;
#pragma unroll
    for (int i = 0; i < 4; ++i) gl_lds16(g + (size_t)32 * i * D3, l + 2048 * i);
  }

  const unsigned short* gVbase = Vt + ((size_t)(bb * 16 + h) * 64 + sr) * 512 + sc;

  const int wm = w * 32;  // wave's 32 q-rows within tile
  f32x4_t o[2][4];
  float m_i[2][4], l_i[2][4];
#pragma unroll
  for (int mi = 0; mi < 2; ++mi)
#pragma unroll
    for (int r = 0; r < 4; ++r) { m_i[mi][r] = -1e30f; l_i[mi][r] = 0.f; }
#pragma unroll
  for (int mi = 0; mi < 2; ++mi)
#pragma unroll
    for (int di = 0; di < 4; ++di) o[mi][di] = (f32x4_t)0.0f;

  const int nkt = (qi + 1) * 2;
  for (int kt = 0; kt < nkt; ++kt) {
    const int k0 = kt * 64;
    __syncthreads();
    // stage K tile [64][64] swizzled
    {
      const unsigned short* g = qkv + base + 1024 + (size_t)(k0 + sr) * D3 + sc;
      unsigned short* l = sK + tid * 8;
      gl_lds16(g, l);
      gl_lds16(g + (size_t)32 * D3, l + 2048);
    }
    // stage Vt tile [64 d][64 k] swizzled (clean rows, no scalar transpose)
    {
      const unsigned short* g = gVbase + k0;
      unsigned short* l = sVt + tid * 8;
      gl_lds16(g, l);
      gl_lds16(g + (size_t)32 * 512, l + 2048);
    }
    __syncthreads();

    const bool active = (k0 <= t0 + wm + 31);
    if (active) {
      // S = Q K^T
      f32x4_t s[2][4];
#pragma unroll
      for (int mi = 0; mi < 2; ++mi)
#pragma unroll
        for (int ni = 0; ni < 4; ++ni) s[mi][ni] = (f32x4_t)0.0f;
#pragma unroll
      for (int kd = 0; kd < 2; ++kd) {
        bf16x8_t aq[2], bk[4];
#pragma unroll
        for (int mi = 0; mi < 2; ++mi) {
          const int rr = wm + mi * 16 + l16;
          aq[mi] = *(const bf16x8_t*)(sQ + rr * 64 + (((kd * 4 + kg) ^ (l16 & 7)) * 8));
        }
#pragma unroll
        for (int ni = 0; ni < 4; ++ni) {
          const int rr = ni * 16 + l16;
          bk[ni] = *(const bf16x8_t*)(sK + rr * 64 + (((kd * 4 + kg) ^ (l16 & 7)) * 8));
        }
#pragma unroll
        for (int mi = 0; mi < 2; ++mi)
#pragma unroll
          for (int ni = 0; ni < 4; ++ni)
            s[mi][ni] = __builtin_amdgcn_mfma_f32_16x16x32_bf16(aq[mi], bk[ni], s[mi][ni], 0, 0, 0);
      }
      // online softmax per row
#pragma unroll
      for (int mi = 0; mi < 2; ++mi) {
#pragma unroll
        for (int r = 0; r < 4; ++r) {
          const int q = t0 + wm + mi * 16 + kg * 4 + r;
          float mx = -1e30f;
#pragma unroll
          for (int ni = 0; ni < 4; ++ni) {
            const int kk = k0 + ni * 16 + l16;
            float v = s[mi][ni][r] * 0.125f;
            v = (kk <= q) ? v : -10000.0f;
            s[mi][ni][r] = v;
            mx = fmaxf(mx, v);
          }
#pragma unroll
          for (int off = 1; off < 16; off <<= 1) mx = fmaxf(mx, __shfl_xor(mx, off, 64));
          const float mo = m_i[mi][r];
          const float mn = fmaxf(mo, mx);
          const float alpha = __expf(mo - mn);
          float ps = 0.f;
#pragma unroll
          for (int ni = 0; ni < 4; ++ni) {
            float p = __expf(s[mi][ni][r] - mn);
            s[mi][ni][r] = p;
            ps += p;
          }
#pragma unroll
          for (int off = 1; off < 16; off <<= 1) ps += __shfl_xor(ps, off, 64);
          l_i[mi][r] = l_i[mi][r] * alpha + ps;
          m_i[mi][r] = mn;
#pragma unroll
          for (int di = 0; di < 4; ++di) o[mi][di][r] *= alpha;
          const int prow = wm + mi * 16 + kg * 4 + r;
#pragma unroll
          for (int ni = 0; ni < 4; ++ni)
            sP[prow * 72 + ni * 16 + l16] = f2bf(s[mi][ni][r]);
        }
      }
      // O += P V   (B-operand = sVt[d][k], vector reads)
#pragma unroll
      for (int kd = 0; kd < 2; ++kd) {
        bf16x8_t ap[2], bv[4];
#pragma unroll
        for (int mi = 0; mi < 2; ++mi)
          ap[mi] = *(const bf16x8_t*)(sP + (wm + mi * 16 + l16) * 72 + kd * 32 + kg * 8);
#pragma unroll
        for (int di = 0; di < 4; ++di) {
          const int dd = di * 16 + l16;
          bv[di] = *(const bf16x8_t*)(sVt + dd * 64 + (((kd * 4 + kg) ^ (l16 & 7)) * 8));
        }
#pragma unroll
        for (int mi = 0; mi < 2; ++mi)
#pragma unroll
          for (int di = 0; di < 4; ++di)
            o[mi][di] = __builtin_amdgcn_mfma_f32_16x16x32_bf16(ap[mi], bv[di], o[mi][di], 0, 0, 0);
      }
    }
  }

  // epilogue: normalize + store bf16
#pragma unroll
  for (int mi = 0; mi < 2; ++mi) {
#pragma unroll
    for (int r = 0; r < 4; ++r) {
      const float inv = 1.0f / l_i[mi][r];
      const int row = t0 + wm + mi * 16 + kg * 4 + r;
      const size_t ob = ((size_t)bb * 512 + row) * 1024 + h * 64;
#pragma unroll
      for (int di = 0; di < 4; ++di)
        outp[ob + di * 16 + l16] = f2bf(o[mi][di][r] * inv);
    }
  }
}

// ---------------- launch ----------------
extern "C" void kernel_launch(void* const* d_in, const int* in_sizes, int n_in,
                              void* d_out, int out_size, void* d_ws, size_t ws_size,
                              hipStream_t stream) {
  const float* x      = (const float*)d_in[0];
  const float* w_qkv  = (const float*)d_in[1];
  const float* w_proj = (const float*)d_in[2];
  const float* w_ff1  = (const float*)d_in[3];
  const float* b_ff1  = (const float*)d_in[4];
  const float* w_ff2  = (const float*)d_in[5];
  const float* b_ff2  = (const float*)d_in[6];
  const float* ln1_g  = (const float*)d_in[7];
  const float* ln1_b  = (const float*)d_in[8];
  const float* ln2_g  = (const float*)d_in[9];
  const float* ln2_b  = (const float*)d_in[10];
  float* out = (float*)d_out;
  char* ws = (char*)d_ws;

  // workspace layout (bytes)
  unsigned short* wqkv_b  = (unsigned short*)(ws + 0);          //  6291456
  unsigned short* wproj_b = (unsigned short*)(ws + 6291456);    //  2097152
  unsigned short* wff1_b  = (unsigned short*)(ws + 8388608);    //  8388608
  unsigned short* wff2_b  = (unsigned short*)(ws + 16777216);   //  8388608
  unsigned short* a_b     = (unsigned short*)(ws + 25165824);   // 16777216 (ln1 out, reused for ln2 out)
  float*          x2_f    = (float*)(ws + 41943040);            // 33554432 (dead until proj)
  unsigned short* vt_b    = (unsigned short*)(ws + 41943040);   // 16777216 alias: live QKV->attn only
  unsigned short* qkv_b   = (unsigned short*)(ws + 75497472);   // 50331648
  unsigned short* attn_b  = (unsigned short*)(ws + 125829120);  // 16777216
  unsigned short* h_b     = qkv_b;                              // 67108864 spans qkv+attn (both dead by FF1)

  // weights fp32 -> bf16 (one fused launch)
  cvt_all<<<12288, 256, 0, stream>>>(w_qkv, wqkv_b, w_proj, wproj_b, w_ff1, wff1_b, w_ff2, wff2_b);

  // LN1
  ln_kernel<<<2048, 256, 0, stream>>>(x, ln1_g, ln1_b, a_b);
  // QKV (V third written transposed to vt_b)
  gemm_bt<0><<<dim3(24, 64), 256, 0, stream>>>(a_b, wqkv_b, nullptr, qkv_b, nullptr, nullptr, vt_b, 8192, 3072, 1024);
  // attention
  attn_kernel<<<dim3(4, 16, 16), 256, 0, stream>>>(qkv_b, vt_b, attn_b);
  // proj + residual
  gemm_bt<1><<<dim3(8, 64), 256, 0, stream>>>(attn_b, wproj_b, x2_f, nullptr, nullptr, x, nullptr, 8192, 1024, 1024);
  // LN2
  ln_kernel<<<2048, 256, 0, stream>>>(x2_f, ln2_g, ln2_b, a_b);
  // FF1 + bias + gelu
  gemm_bt<2><<<dim3(32, 64), 256, 0, stream>>>(a_b, wff1_b, nullptr, h_b, b_ff1, nullptr, nullptr, 8192, 4096, 1024);
  // FF2 + bias + residual
  gemm_bt<3><<<dim3(8, 64), 256, 0, stream>>>(h_b, wff2_b, out, nullptr, b_ff2, x2_f, nullptr, 8192, 1024, 4096);
}

// Round 9
// 475.873 us; speedup vs baseline: 1.2129x; 1.0045x over previous
//
#include <hip/hip_runtime.h>
#include <stdint.h>

typedef __bf16 bf16x8_t __attribute__((ext_vector_type(8)));
typedef float f32x4_t __attribute__((ext_vector_type(4)));
typedef unsigned short ushort8_t __attribute__((ext_vector_type(8)));

#define DEV __device__ __forceinline__

DEV unsigned short f2bf(float f) {
  union { float f; uint32_t u; } v; v.f = f;
  uint32_t r = v.u + 0x7FFFu + ((v.u >> 16) & 1u);
  return (unsigned short)(r >> 16);
}

// NOTE: the intrinsic's offset arg applies to BOTH global and LDS address
// (R6 failure: absmax 984). Keep it 0 always.
DEV void gl_lds16(const void* g, void* l) {
  __builtin_amdgcn_global_load_lds(
      (const __attribute__((address_space(1))) void*)g,
      (__attribute__((address_space(3))) void*)l, 16, 0, 0);
}

// exact-gelu via branch-free A&S 7.1.26 erf (max err 1.5e-7)
DEV float gelu_f(float x) {
  const float y = x * 0.7071067811865475f;
  const float ay = fabsf(y);
  const float t = __builtin_amdgcn_rcpf(1.0f + 0.3275911f * ay);
  float p = fmaf(t, 1.061405429f, -1.453152027f);
  p = fmaf(t, p, 1.421413741f);
  p = fmaf(t, p, -0.284496736f);
  p = fmaf(t, p, 0.254829592f);
  p *= t;
  const float e = __expf(-ay * ay);
  float erfv = 1.0f - p * e;
  erfv = copysignf(erfv, y);
  return 0.5f * x * (1.0f + erfv);
}

// ---------------- fused weight fp32 -> bf16 ----------------
__global__ __launch_bounds__(256) void cvt_all(const float* __restrict__ w0, unsigned short* __restrict__ o0,
                                               const float* __restrict__ w1, unsigned short* __restrict__ o1,
                                               const float* __restrict__ w2, unsigned short* __restrict__ o2,
                                               const float* __restrict__ w3, unsigned short* __restrict__ o3) {
  int i = blockIdx.x * 256 + threadIdx.x;
  const float* in; unsigned short* outp;
  if (i < 786432) { in = w0; outp = o0; }
  else if (i < 1048576) { in = w1; outp = o1; i -= 786432; }
  else if (i < 2097152) { in = w2; outp = o2; i -= 1048576; }
  else { in = w3; outp = o3; i -= 2097152; }
  float4 v = ((const float4*)in)[i];
  ushort4 o;
  o.x = f2bf(v.x); o.y = f2bf(v.y); o.z = f2bf(v.z); o.w = f2bf(v.w);
  ((ushort4*)outp)[i] = o;
}

// ---------------- layernorm fp32 -> bf16 (1024 cols, wave per row) ----------------
__global__ __launch_bounds__(256) void ln_kernel(const float* __restrict__ x,
                                                 const float* __restrict__ g,
                                                 const float* __restrict__ b,
                                                 unsigned short* __restrict__ outp) {
  const int row = blockIdx.x * 4 + (threadIdx.x >> 6);
  const int lane = threadIdx.x & 63;
  const float4* xr = (const float4*)(x + (size_t)row * 1024);
  float4 v[4];
  float s = 0.f, s2 = 0.f;
#pragma unroll
  for (int j = 0; j < 4; ++j) {
    v[j] = xr[j * 64 + lane];
    s += v[j].x + v[j].y + v[j].z + v[j].w;
    s2 += v[j].x * v[j].x + v[j].y * v[j].y + v[j].z * v[j].z + v[j].w * v[j].w;
  }
#pragma unroll
  for (int off = 1; off < 64; off <<= 1) {
    s += __shfl_xor(s, off, 64);
    s2 += __shfl_xor(s2, off, 64);
  }
  const float mu = s * (1.0f / 1024.0f);
  const float var = s2 * (1.0f / 1024.0f) - mu * mu;
  const float rstd = rsqrtf(var + 1e-5f);
  ushort4* orow = (ushort4*)(outp + (size_t)row * 1024);
  const float4* gp = (const float4*)g;
  const float4* bp = (const float4*)b;
#pragma unroll
  for (int j = 0; j < 4; ++j) {
    float4 gv = gp[j * 64 + lane], bv = bp[j * 64 + lane];
    ushort4 o;
    o.x = f2bf((v[j].x - mu) * rstd * gv.x + bv.x);
    o.y = f2bf((v[j].y - mu) * rstd * gv.y + bv.y);
    o.z = f2bf((v[j].z - mu) * rstd * gv.z + bv.z);
    o.w = f2bf((v[j].w - mu) * rstd * gv.w + bv.w);
    orow[j * 64 + lane] = o;
  }
}

// ---------------- GEMM: C[M,N] = A[M,K] * B[N,K]^T, bf16 in, fp32 acc ----------------
// R4-proven K-loop: BK=32, double-buffered LDS, one barrier per iter.
// BM template: 128 (4x4 acc/wave) for large-N GEMMs; 64 (2x4 acc/wave) for
// N=1024 GEMMs -> 1024 blocks = 4 blocks/CU (fixes grid-residency bound seen
// in R8: FF2 at 2 blocks/CU, Occupancy 21%).
// Swizzle (0 conflicts, verified R2): phys chunk = kc ^ ((row>>1)&3).
// Column-major block order: consecutive blocks share one 128-col B-stripe.
// MODE 0: bf16 C; V-third (col>=2048) transposed to Vt[b,h,d,t]   (QKV)
// MODE 1: fp32 C = acc + res                                      (proj + residual)
// MODE 2: bf16 C = gelu(acc + bias)                               (FF1)
// MODE 3: fp32 C = acc + bias + res                               (FF2 + residual)
template <int MODE, int BM>
__global__ __launch_bounds__(256) void gemm_bt(const unsigned short* __restrict__ A,
                                               const unsigned short* __restrict__ B,
                                               float* __restrict__ Cf,
                                               unsigned short* __restrict__ Cb,
                                               const float* __restrict__ bias,
                                               const float* __restrict__ res,
                                               unsigned short* __restrict__ Vt,
                                               int M, int N, int K) {
  constexpr int MI = BM / 32;       // m-frags per wave (wave tile BM/2 x 64)
  constexpr int RT = 8192 / BM;     // row tiles (M is always 8192)
  constexpr int ABUF = BM * 32;     // shorts per A buffer
  __shared__ unsigned short sA[2][ABUF];
  __shared__ unsigned short sB[2][128 * 32];
  const int tid = threadIdx.x;
  const int w = tid >> 6, lane = tid & 63;
  const int kg = lane >> 4, l16 = lane & 15;
  const int wm = (w & 1) * (BM / 2), wn = (w >> 1) * 64;

  // column-major block ordering: consecutive cid -> same 128-col stripe
  const int cid = blockIdx.y * gridDim.x + blockIdx.x;
  const int colBase = (cid / RT) * 128;
  const int rowBase = (cid % RT) * BM;

  // staging map: thread covers (row sr [+64], phys chunk tid&3)
  const int sr = (BM == 128) ? (tid >> 2) : ((tid >> 2) & 63);
  const int gc = ((tid & 3) ^ ((sr >> 1) & 3)) * 8;   // swizzled global k-chunk
  const unsigned short* gA = A + (size_t)(rowBase + sr) * K + gc;
  const unsigned short* gB = B + (size_t)(colBase + sr) * K + gc;

  f32x4_t acc[MI][4];
#pragma unroll
  for (int mi = 0; mi < MI; ++mi)
#pragma unroll
    for (int ni = 0; ni < 4; ++ni) acc[mi][ni] = (f32x4_t)0.0f;

  // fragment read offsets within one buffer (shorts)
  int offA[MI], offB[4];
  const int pc = (kg ^ ((l16 >> 1) & 3)) * 8;
#pragma unroll
  for (int i = 0; i < MI; ++i) offA[i] = (wm + i * 16 + l16) * 32 + pc;
#pragma unroll
  for (int i = 0; i < 4; ++i) offB[i] = (wn + i * 16 + l16) * 32 + pc;

  // prologue: tile 0 -> buf 0
  gl_lds16(gA, &sA[0][tid * 8]);
  if (BM == 128) gl_lds16(gA + (size_t)64 * K, &sA[0][2048 + tid * 8]);
  gl_lds16(gB, &sB[0][tid * 8]);
  gl_lds16(gB + (size_t)64 * K, &sB[0][2048 + tid * 8]);
  gA += 32; gB += 32;

  const int nk = K >> 5;
  for (int kt = 0; kt < nk; ++kt) {
    __syncthreads();  // drains loads for tile kt (in flight during compute kt-1)
    if (kt + 1 < nk) {
      const int nb = (kt + 1) & 1;
      gl_lds16(gA, &sA[nb][tid * 8]);
      if (BM == 128) gl_lds16(gA + (size_t)64 * K, &sA[nb][2048 + tid * 8]);
      gl_lds16(gB, &sB[nb][tid * 8]);
      gl_lds16(gB + (size_t)64 * K, &sB[nb][2048 + tid * 8]);
      gA += 32; gB += 32;
    }
    const int par = kt & 1;
    bf16x8_t a[MI], b[4];
#pragma unroll
    for (int i = 0; i < MI; ++i) a[i] = *(const bf16x8_t*)(&sA[par][0] + offA[i]);
#pragma unroll
    for (int i = 0; i < 4; ++i) b[i] = *(const bf16x8_t*)(&sB[par][0] + offB[i]);
#pragma unroll
    for (int mi = 0; mi < MI; ++mi)
#pragma unroll
      for (int ni = 0; ni < 4; ++ni)
        acc[mi][ni] = __builtin_amdgcn_mfma_f32_16x16x32_bf16(a[mi], b[ni], acc[mi][ni], 0, 0, 0);
  }

#pragma unroll
  for (int mi = 0; mi < MI; ++mi) {
#pragma unroll
    for (int ni = 0; ni < 4; ++ni) {
      const int col = colBase + wn + ni * 16 + l16;
      if (MODE == 0 && colBase >= 2048) {
        // V third -> Vt[b,h,d,t]; r-quad is t-contiguous -> ushort4 store
        const int c2 = col - 2048;
        const int hh = c2 >> 6, dd = c2 & 63;
        const int rw = rowBase + wm + mi * 16 + kg * 4;
        ushort4 pk;
        pk.x = f2bf(acc[mi][ni][0]);
        pk.y = f2bf(acc[mi][ni][1]);
        pk.z = f2bf(acc[mi][ni][2]);
        pk.w = f2bf(acc[mi][ni][3]);
        *(ushort4*)(Vt + (((size_t)(rw >> 9) * 16 + hh) * 64 + dd) * 512 + (rw & 511)) = pk;
        continue;
      }
      float bv = 0.f;
      if (MODE == 2 || MODE == 3) bv = bias[col];
#pragma unroll
      for (int r = 0; r < 4; ++r) {
        const int row = rowBase + wm + mi * 16 + kg * 4 + r;
        const size_t idx = (size_t)row * N + col;
        float v = acc[mi][ni][r];
        if (MODE == 0) {
          Cb[idx] = f2bf(v);
        } else if (MODE == 1) {
          Cf[idx] = v + res[idx];
        } else if (MODE == 2) {
          Cb[idx] = f2bf(gelu_f(v + bv));
        } else {
          Cf[idx] = v + bv + res[idx];
        }
      }
    }
  }
}

// ---------------- causal flash attention ----------------
// qkv: [8192, 3072] bf16 (q | k cols; V comes from Vt[b,h,d,t]); out: [8192, 1024] bf16
// sQ/sK/sVt XOR-swizzled: physical chunk for (row r, chunk c in 0..7) = c ^ (r&7)
// Softmax WITHOUT max-subtraction (|S*scale| <~ 15, exp can't overflow; masked
// lanes -> exp(-1250) = 0 exact). Row-sum l comes FREE from the PV MFMA with an
// all-ones B fragment (all 16 output cols equal Σp). No shuffles in the loop.
__global__ __launch_bounds__(256) void attn_kernel(const unsigned short* __restrict__ qkv,
                                                   const unsigned short* __restrict__ Vt,
                                                   unsigned short* __restrict__ outp) {
  constexpr int D3 = 3072;
  __shared__ unsigned short sQ[128 * 64];
  __shared__ unsigned short sK[64 * 64];
  __shared__ unsigned short sVt[64 * 64];   // [d][k-slice]
  __shared__ unsigned short sP[128 * 72];   // [q][k], stride 72
  const int tid = threadIdx.x;
  const int w = tid >> 6, lane = tid & 63;
  const int kg = lane >> 4, l16 = lane & 15;
  const int qi = blockIdx.x, h = blockIdx.y, bb = blockIdx.z;
  const int t0 = qi * 128;
  const size_t base = (size_t)bb * 512 * D3 + h * 64;

  const int sr = tid >> 3;                           // staging row within 32-row slab
  const int sc = ((tid & 7) ^ (sr & 7)) * 8;         // swizzled k-chunk (shorts)

  // stage Q (rows t0..t0+127)
  {
    const unsigned short* g = qkv + base + (size_t)(t0 + sr) * D3 + sc;
    unsigned short* l = sQ + tid * 8;
#pragma unroll
    for (int i = 0; i < 4; ++i) gl_lds16(g + (size_t)32 * i * D3, l + 2048 * i);
  }

  const unsigned short* gVbase = Vt + ((size_t)(bb * 16 + h) * 64 + sr) * 512 + sc;

  bf16x8_t ones;
#pragma unroll
  for (int j = 0; j < 8; ++j) ones[j] = (__bf16)1.0f;

  const int wm = w * 32;  // wave's 32 q-rows within tile
  f32x4_t o[2][4];
  f32x4_t lsum[2];        // row sums, accumulated by MFMA across all tiles
#pragma unroll
  for (int mi = 0; mi < 2; ++mi) {
    lsum[mi] = (f32x4_t)0.0f;
#pragma unroll
    for (int di = 0; di < 4; ++di) o[mi][di] = (f32x4_t)0.0f;
  }

  const int nkt = (qi + 1) * 2;
  for (int kt = 0; kt < nkt; ++kt) {
    const int k0 = kt * 64;
    __syncthreads();
    // stage K tile [64][64] swizzled
    {
      const unsigned short* g = qkv + base + 1024 + (size_t)(k0 + sr) * D3 + sc;
      unsigned short* l = sK + tid * 8;
      gl_lds16(g, l);
      gl_lds16(g + (size_t)32 * D3, l + 2048);
    }
    // stage Vt tile [64 d][64 k] swizzled
    {
      const unsigned short* g = gVbase + k0;
      unsigned short* l = sVt + tid * 8;
      gl_lds16(g, l);
      gl_lds16(g + (size_t)32 * 512, l + 2048);
    }
    __syncthreads();

    const bool active = (k0 <= t0 + wm + 31);
    if (active) {
      // S = Q K^T
      f32x4_t s[2][4];
#pragma unroll
      for (int mi = 0; mi < 2; ++mi)
#pragma unroll
        for (int ni = 0; ni < 4; ++ni) s[mi][ni] = (f32x4_t)0.0f;
#pragma unroll
      for (int kd = 0; kd < 2; ++kd) {
        bf16x8_t aq[2], bk[4];
#pragma unroll
        for (int mi = 0; mi < 2; ++mi) {
          const int rr = wm + mi * 16 + l16;
          aq[mi] = *(const bf16x8_t*)(sQ + rr * 64 + (((kd * 4 + kg) ^ (l16 & 7)) * 8));
        }
#pragma unroll
        for (int ni = 0; ni < 4; ++ni) {
          const int rr = ni * 16 + l16;
          bk[ni] = *(const bf16x8_t*)(sK + rr * 64 + (((kd * 4 + kg) ^ (l16 & 7)) * 8));
        }
#pragma unroll
        for (int mi = 0; mi < 2; ++mi)
#pragma unroll
          for (int ni = 0; ni < 4; ++ni)
            s[mi][ni] = __builtin_amdgcn_mfma_f32_16x16x32_bf16(aq[mi], bk[ni], s[mi][ni], 0, 0, 0);
      }
      // unnormalized masked softmax: p = exp(s*scale), straight to sP
#pragma unroll
      for (int mi = 0; mi < 2; ++mi) {
#pragma unroll
        for (int r = 0; r < 4; ++r) {
          const int q = t0 + wm + mi * 16 + kg * 4 + r;
          const int prow = wm + mi * 16 + kg * 4 + r;
#pragma unroll
          for (int ni = 0; ni < 4; ++ni) {
            const int kk = k0 + ni * 16 + l16;
            const float p = (kk <= q) ? __expf(s[mi][ni][r] * 0.125f) : 0.0f;
            sP[prow * 72 + ni * 16 + l16] = f2bf(p);
          }
        }
      }
      // O += P V ; lsum += P 1  (ones B-fragment: every output col = Σp)
#pragma unroll
      for (int kd = 0; kd < 2; ++kd) {
        bf16x8_t ap[2], bv[4];
#pragma unroll
        for (int mi = 0; mi < 2; ++mi)
          ap[mi] = *(const bf16x8_t*)(sP + (wm + mi * 16 + l16) * 72 + kd * 32 + kg * 8);
#pragma unroll
        for (int di = 0; di < 4; ++di) {
          const int dd = di * 16 + l16;
          bv[di] = *(const bf16x8_t*)(sVt + dd * 64 + (((kd * 4 + kg) ^ (l16 & 7)) * 8));
        }
#pragma unroll
        for (int mi = 0; mi < 2; ++mi) {
#pragma unroll
          for (int di = 0; di < 4; ++di)
            o[mi][di] = __builtin_amdgcn_mfma_f32_16x16x32_bf16(ap[mi], bv[di], o[mi][di], 0, 0, 0);
          lsum[mi] = __builtin_amdgcn_mfma_f32_16x16x32_bf16(ap[mi], ones, lsum[mi], 0, 0, 0);
        }
      }
    }
  }

  // epilogue: normalize + store bf16
#pragma unroll
  for (int mi = 0; mi < 2; ++mi) {
#pragma unroll
    for (int r = 0; r < 4; ++r) {
      const float inv = 1.0f / lsum[mi][r];
      const int row = t0 + wm + mi * 16 + kg * 4 + r;
      const size_t ob = ((size_t)bb * 512 + row) * 1024 + h * 64;
#pragma unroll
      for (int di = 0; di < 4; ++di)
        outp[ob + di * 16 + l16] = f2bf(o[mi][di][r] * inv);
    }
  }
}

// ---------------- launch ----------------
extern "C" void kernel_launch(void* const* d_in, const int* in_sizes, int n_in,
                              void* d_out, int out_size, void* d_ws, size_t ws_size,
                              hipStream_t stream) {
  const float* x      = (const float*)d_in[0];
  const float* w_qkv  = (const float*)d_in[1];
  const float* w_proj = (const float*)d_in[2];
  const float* w_ff1  = (const float*)d_in[3];
  const float* b_ff1  = (const float*)d_in[4];
  const float* w_ff2  = (const float*)d_in[5];
  const float* b_ff2  = (const float*)d_in[6];
  const float* ln1_g  = (const float*)d_in[7];
  const float* ln1_b  = (const float*)d_in[8];
  const float* ln2_g  = (const float*)d_in[9];
  const float* ln2_b  = (const float*)d_in[10];
  float* out = (float*)d_out;
  char* ws = (char*)d_ws;

  // workspace layout (bytes)
  unsigned short* wqkv_b  = (unsigned short*)(ws + 0);          //  6291456
  unsigned short* wproj_b = (unsigned short*)(ws + 6291456);    //  2097152
  unsigned short* wff1_b  = (unsigned short*)(ws + 8388608);    //  8388608
  unsigned short* wff2_b  = (unsigned short*)(ws + 16777216);   //  8388608
  unsigned short* a_b     = (unsigned short*)(ws + 25165824);   // 16777216 (ln1 out, reused for ln2 out)
  float*          x2_f    = (float*)(ws + 41943040);            // 33554432 (dead until proj)
  unsigned short* vt_b    = (unsigned short*)(ws + 41943040);   // 16777216 alias: live QKV->attn only
  unsigned short* qkv_b   = (unsigned short*)(ws + 75497472);   // 50331648
  unsigned short* attn_b  = (unsigned short*)(ws + 125829120);  // 16777216
  unsigned short* h_b     = qkv_b;                              // 67108864 spans qkv+attn (both dead by FF1)

  // weights fp32 -> bf16 (one fused launch)
  cvt_all<<<12288, 256, 0, stream>>>(w_qkv, wqkv_b, w_proj, wproj_b, w_ff1, wff1_b, w_ff2, wff2_b);

  // LN1
  ln_kernel<<<2048, 256, 0, stream>>>(x, ln1_g, ln1_b, a_b);
  // QKV (V third written transposed to vt_b)
  gemm_bt<0, 128><<<dim3(24, 64), 256, 0, stream>>>(a_b, wqkv_b, nullptr, qkv_b, nullptr, nullptr, vt_b, 8192, 3072, 1024);
  // attention
  attn_kernel<<<dim3(4, 16, 16), 256, 0, stream>>>(qkv_b, vt_b, attn_b);
  // proj + residual (BM=64 -> 1024 blocks, 4/CU)
  gemm_bt<1, 64><<<dim3(8, 128), 256, 0, stream>>>(attn_b, wproj_b, x2_f, nullptr, nullptr, x, nullptr, 8192, 1024, 1024);
  // LN2
  ln_kernel<<<2048, 256, 0, stream>>>(x2_f, ln2_g, ln2_b, a_b);
  // FF1 + bias + gelu
  gemm_bt<2, 128><<<dim3(32, 64), 256, 0, stream>>>(a_b, wff1_b, nullptr, h_b, b_ff1, nullptr, nullptr, 8192, 4096, 1024);
  // FF2 + bias + residual (BM=64 -> 1024 blocks, 4/CU)
  gemm_bt<3, 64><<<dim3(8, 128), 256, 0, stream>>>(h_b, wff2_b, out, nullptr, b_ff2, x2_f, nullptr, 8192, 1024, 4096);
}